// Round 9
// baseline (130.436 us; speedup 1.0000x reference)
//
#include <hip/hip_runtime.h>
#include <stdint.h>
#include <stddef.h>

// Problem constants
#define NB   16
#define NC   64
#define NH   64
#define NW   64
#define KC   16
#define NOUT 64
#define NRANK 8
#define NMLP 32
#define NF   576      // C*3*3
#define NPIX 4096     // H*W
#define XH   66       // halo height/width for channel-last copy
#define OROWS 8192    // interleaved outc rows per image (row = slot*16 + k)

typedef short s16x8 __attribute__((ext_vector_type(8)));
typedef short s16x4 __attribute__((ext_vector_type(4)));
typedef float f32x4 __attribute__((ext_vector_type(4)));

__device__ __forceinline__ unsigned short f2bf(float x) {
    union { float f; uint32_t u; } v; v.f = x;
    uint32_t r = v.u + 0x7FFFu + ((v.u >> 16) & 1u);   // RTNE
    return (unsigned short)(r >> 16);
}
__device__ __forceinline__ float bf2f(unsigned short u) {
    union { uint32_t u; float f; } v; v.u = ((uint32_t)u) << 16;
    return v.f;
}

// ---------------------------------------------------------------------------
// k_prep_all (R0 exact): blocks [0,1056): xcl; [1056,1128): basekF.
// ---------------------------------------------------------------------------
extern "C" __global__ __launch_bounds__(256)
void k_prep_all(const float* __restrict__ x, const float* __restrict__ basek,
                unsigned short* __restrict__ xcl, unsigned short* __restrict__ basekF)
{
    __shared__ float tile[64 * 65];
    const int blk0 = blockIdx.x;
    const int tid = threadIdx.x;
    if (blk0 < XH * 16) {
        const int b = blk0 & 15, yy = blk0 >> 4;
        unsigned short* dst = xcl + ((size_t)(b * XH + yy) * XH) * 64;
        if (yy == 0 || yy == XH - 1) {
            for (int e = tid; e < XH * 64; e += 256) dst[e] = 0;
            return;
        }
        const int y = yy - 1;
        const float* src = x + (size_t)b * NC * (NH * NW) + y * NW;
        #pragma unroll
        for (int rr = 0; rr < 16; ++rr) {
            int c = rr * 4 + (tid >> 6);
            int xx = tid & 63;
            tile[c * 65 + xx] = src[(size_t)c * (NH * NW) + xx];
        }
        __syncthreads();
        for (int ee = tid; ee < 528; ee += 256) {
            int xx = ee >> 3;
            int c0 = (ee & 7) * 8;
            s16x8 v;
            #pragma unroll
            for (int j = 0; j < 8; ++j) {
                float f = (xx == 0 || xx == XH - 1) ? 0.f : tile[(c0 + j) * 65 + (xx - 1)];
                v[j] = (short)f2bf(f);
            }
            *reinterpret_cast<s16x8*>(dst + ee * 8) = v;
        }
    } else {
        const int blk = blk0 - XH * 16;    // ks*4 + wv
        const int ks = blk >> 2, wv = blk & 3;
        unsigned short outv[16];
        #pragma unroll
        for (int i = 0; i < 16; ++i) {
            int e = tid * 16 + i;          // e = r*512 + lane*8 + j
            int r = e >> 9;
            int lane = (e >> 3) & 63;
            int j = e & 7;
            int col = wv * 16 + (lane & 15);
            int fp = (lane >> 4) * 8 + ks * 32 + j;
            int tap = fp >> 6, c = fp & 63;
            outv[i] = f2bf(basek[((size_t)r * NF + c * 9 + tap) * NOUT + col]);
        }
        unsigned short* dst = basekF + (size_t)blk * 4096 + tid * 16;
        #pragma unroll
        for (int i = 0; i < 16; ++i) dst[i] = outv[i];
    }
}

// ---------------------------------------------------------------------------
// k_cm (R9): fused centers+main, one block per (b,k), 1024 threads.
// R9 changes vs R8:
//  - MLP layer-1 widened to 1024 threads (32 chunks x 18 feats); p1/pb (4 KB
//    each) moved into the Wl region (dead until W-expansion).
//  - GEMM async-STAGE split (T14): next tile's 9 global loads issued into
//    named registers right after the first barrier; ds_write at the top of
//    the next iteration. L2 latency hides under MFMA+stores+barrier.
//    (+36 VGPR — free: LDS pins 1 block/CU = 4 waves/SIMD => 128 VGPR budget.)
// Dynamic LDS 157,952 B:
//   list @0 (8192, live all phases) | wcnt @8192 | wsum @8256 (36864)
//   cbuf @45120 (2304) | h1/h2/hb/lrs @49472..49888
//   p1 @51200 (4096), pb @55296 (4096)  [overlap Wl; dead before W-exp]
//   Wl @51200 (73728, dead after bfr load) | albuf @8192+sg*37376 (x4)
//   biasl @157696 (256)
// ---------------------------------------------------------------------------
extern "C" __global__ __launch_bounds__(1024, 1)
void k_cm(const unsigned short* __restrict__ xcl, const int* __restrict__ labels,
          const float* __restrict__ lw1, const float* __restrict__ lb1,
          const float* __restrict__ lw2, const float* __restrict__ lb2,
          const float* __restrict__ lw3, const float* __restrict__ lb3,
          const float* __restrict__ bw1, const float* __restrict__ bb1,
          const float* __restrict__ bw2, const float* __restrict__ bb2,
          const unsigned short* __restrict__ basekF,
          unsigned short* __restrict__ slotmap, unsigned short* __restrict__ outc)
{
    extern __shared__ __align__(16) char smem[];
    unsigned short* list = (unsigned short*)smem;
    int*   wcnt  = (int*)(smem + 8192);
    float* wsum  = (float*)(smem + 8256);
    float* cbuf  = (float*)(smem + 45120);
    float* h1    = (float*)(smem + 49472);
    float* h2    = (float*)(smem + 49600);
    float* hb    = (float*)(smem + 49728);
    float* lrs   = (float*)(smem + 49856);
    float* p1    = (float*)(smem + 51200);   // 32*32*4, overlaps Wl (dead later)
    float* pb    = (float*)(smem + 55296);   // 32*32*4
    unsigned short* Wl = (unsigned short*)(smem + 51200);
    float* biasl = (float*)(smem + 157696);

    const int bk = blockIdx.x;
    const int b = bk & 15, k = bk >> 4;
    const int tid = threadIdx.x;
    const int lane = tid & 63, wv = tid >> 6;    // wv 0..15
    const int st = tid & 255, sg = tid >> 8;     // 4 sub-groups of 256
    const int* lab = labels + b * NPIX;

    // ---- unordered single-atomic compaction (R8)
    if (tid == 0) wcnt[0] = 0;
    __syncthreads();
    {
        const int n0 = tid, n1 = 1024 + tid, n2 = 2048 + tid, n3 = 3072 + tid;
        const int l0 = lab[n0], l1 = lab[n1], l2 = lab[n2], l3 = lab[n3];
        const bool q0 = (l0 == k), q1 = (l1 == k), q2 = (l2 == k), q3 = (l3 == k);
        const unsigned long long m0 = __ballot(q0), m1 = __ballot(q1),
                                 m2 = __ballot(q2), m3 = __ballot(q3);
        const int c0 = __popcll(m0), c1 = __popcll(m1),
                  c2 = __popcll(m2), c3 = __popcll(m3);
        int base = 0;
        if (lane == 0)
            base = __hip_atomic_fetch_add(&wcnt[0], c0 + c1 + c2 + c3,
                                          __ATOMIC_RELAXED, __HIP_MEMORY_SCOPE_WORKGROUP);
        base = __shfl(base, 0);
        const unsigned long long lt = (1ull << lane) - 1ull;
        if (q0) { int s = base + __popcll(m0 & lt);
                  list[s] = (unsigned short)n0; slotmap[b * NPIX + n0] = (unsigned short)s; }
        base += c0;
        if (q1) { int s = base + __popcll(m1 & lt);
                  list[s] = (unsigned short)n1; slotmap[b * NPIX + n1] = (unsigned short)s; }
        base += c1;
        if (q2) { int s = base + __popcll(m2 & lt);
                  list[s] = (unsigned short)n2; slotmap[b * NPIX + n2] = (unsigned short)s; }
        base += c2;
        if (q3) { int s = base + __popcll(m3 & lt);
                  list[s] = (unsigned short)n3; slotmap[b * NPIX + n3] = (unsigned short)s; }
    }
    __syncthreads();
    const int cnt = wcnt[0];

    // ---- gather: wave wv handles pixels i = wv, wv+16, ...; lane = channel
    float s00 = 0.f, s01 = 0.f, s02 = 0.f,
          s10 = 0.f, s11 = 0.f, s12 = 0.f,
          s20 = 0.f, s21 = 0.f, s22 = 0.f;
    const unsigned short* xb0 = xcl + (size_t)b * (XH * XH * 64) + lane;
    #pragma unroll 4
    for (int i = wv; i < cnt; i += 16) {
        int n = list[i];
        const unsigned short* p0 = xb0 + (((n >> 6) * XH) + (n & 63)) * 64;
        s00 += bf2f(p0[0]);
        s01 += bf2f(p0[64]);
        s02 += bf2f(p0[128]);
        const unsigned short* prow1 = p0 + XH * 64;
        s10 += bf2f(prow1[0]);
        s11 += bf2f(prow1[64]);
        s12 += bf2f(prow1[128]);
        const unsigned short* prow2 = p0 + 2 * XH * 64;
        s20 += bf2f(prow2[0]);
        s21 += bf2f(prow2[64]);
        s22 += bf2f(prow2[128]);
    }
    {
        float* wrow = wsum + wv * 576 + lane;
        wrow[0 * 64] = s00; wrow[1 * 64] = s01; wrow[2 * 64] = s02;
        wrow[3 * 64] = s10; wrow[4 * 64] = s11; wrow[5 * 64] = s12;
        wrow[6 * 64] = s20; wrow[7 * 64] = s21; wrow[8 * 64] = s22;
    }
    __syncthreads();

    // ---- reduce 16 waves -> centers (feature order c*9+tap)
    const float inv = 1.f / ((float)cnt + 1e-6f);
    if (tid < NF) {
        int tap = tid >> 6, c = tid & 63;
        float s = 0.f;
        #pragma unroll
        for (int w = 0; w < 16; ++w) s += wsum[w * 576 + tap * 64 + c];
        cbuf[c * 9 + tap] = s * inv;
    }
    __syncthreads();

    // ---- fused MLPs (layer-1 widened: 1024 threads, 32 chunks x 18 feats)
    {
        const int j = tid & 31, ch = tid >> 5;       // ch 0..31
        float a1 = 0.f, a2 = 0.f;
        #pragma unroll
        for (int i = 0; i < 18; ++i) {
            int f = ch * 18 + i;
            float cv = cbuf[f];
            a1 += cv * lw1[f * NMLP + j];
            a2 += cv * bw1[f * NMLP + j];
        }
        p1[ch * NMLP + j] = a1; pb[ch * NMLP + j] = a2;
    }
    __syncthreads();
    if (tid < NMLP) {
        float a = lb1[tid];
        #pragma unroll
        for (int i = 0; i < 32; ++i) a += p1[i * NMLP + tid];
        h1[tid] = fmaxf(a, 0.f);
    } else if (tid < 2 * NMLP) {
        int j = tid - NMLP;
        float a = bb1[j];
        #pragma unroll
        for (int i = 0; i < 32; ++i) a += pb[i * NMLP + j];
        hb[j] = fmaxf(a, 0.f);
    }
    __syncthreads();
    if (tid < NMLP) {
        float a = lb2[tid];
        for (int i = 0; i < NMLP; ++i) a += h1[i] * lw2[i * NMLP + tid];
        h2[tid] = fmaxf(a, 0.f);
    } else if (tid >= 64 && tid < 128) {
        int o = tid - 64;
        float a = bb2[o];
        for (int i = 0; i < NMLP; ++i) a += hb[i] * bw2[i * NOUT + o];
        biasl[o] = a;                           // LDS, not global
    }
    __syncthreads();
    if (tid < NRANK) {
        float a = lb3[tid];
        for (int i = 0; i < NMLP; ++i) a += h2[i] * lw3[i * NRANK + tid];
        lrs[tid] = a;
    }
    __syncthreads();

    // ---- W-expansion into LDS Wl (R13-proven math, identical rounding)
    {
        float l8[NRANK];
        #pragma unroll
        for (int r = 0; r < NRANK; ++r) l8[r] = lrs[r];
        #pragma unroll 2
        for (int q = 0; q < 5; ++q) {
            int m = q * 1024 + tid;            // 0..4607 valid
            if (m < 4608) {
                int ks = m >> 8, t = m & 255;
                const unsigned short* src = basekF
                    + ((size_t)(ks * 4 + (t >> 6)) * 8) * 512 + (t & 63) * 8;
                float w[8] = {0.f, 0.f, 0.f, 0.f, 0.f, 0.f, 0.f, 0.f};
                #pragma unroll
                for (int r = 0; r < NRANK; ++r) {
                    s16x8 bv = *reinterpret_cast<const s16x8*>(src + r * 512);
                    #pragma unroll
                    for (int j = 0; j < 8; ++j)
                        w[j] += l8[r] * bf2f((unsigned short)bv[j]);
                }
                s16x8 f;
                #pragma unroll
                for (int j = 0; j < 8; ++j) f[j] = (short)f2bf(w[j]);
                *reinterpret_cast<s16x8*>(Wl + m * 8) = f;
            }
        }
    }
    __syncthreads();

    // ---- load B-fragments from Wl into registers, then free Wl for albufs
    s16x8 bfr[18];
    #pragma unroll
    for (int ks = 0; ks < 18; ++ks)
        bfr[ks] = *reinterpret_cast<const s16x8*>(Wl + ks * 2048 + st * 8);
    __syncthreads();

    // ---- main GEMM (R12 tiling, 4 sub-groups; async-STAGE issue-early/
    //      write-late; output rows interleaved)
    {
        const int wv4 = (tid >> 6) & 3;
        const int quad = lane >> 4, l16 = lane & 15;
        unsigned short* albuf = (unsigned short*)(smem + 8192 + sg * 37376);
        const int col = wv4 * 16 + l16;
        const float bb = biasl[col];
        const unsigned short* xb = xcl + (size_t)b * (XH * XH * 64);
        const int p = st >> 3, part = st & 7;
        const int ntile = (cnt + 31) >> 5;
        const int niter = (ntile + 3) >> 2;
        unsigned short* ob = outc + (size_t)b * (OROWS * 64);
        unsigned short* arow = albuf + p * 584 + part * 8;

        s16x8 t0_, t1_, t2_, t3_, t4_, t5_, t6_, t7_, t8_;
        #define ISSUE(ITER) do { \
            int slot_ = (((ITER) * 4 + sg) << 5) + p; \
            int n_ = (slot_ < cnt) ? (int)list[slot_] : 0; \
            const unsigned short* xr_ = xb + (((n_ >> 6) * XH) + (n_ & 63)) * 64 + part * 8; \
            t0_ = *reinterpret_cast<const s16x8*>(xr_ + (0 * XH + 0) * 64); \
            t1_ = *reinterpret_cast<const s16x8*>(xr_ + (0 * XH + 1) * 64); \
            t2_ = *reinterpret_cast<const s16x8*>(xr_ + (0 * XH + 2) * 64); \
            t3_ = *reinterpret_cast<const s16x8*>(xr_ + (1 * XH + 0) * 64); \
            t4_ = *reinterpret_cast<const s16x8*>(xr_ + (1 * XH + 1) * 64); \
            t5_ = *reinterpret_cast<const s16x8*>(xr_ + (1 * XH + 2) * 64); \
            t6_ = *reinterpret_cast<const s16x8*>(xr_ + (2 * XH + 0) * 64); \
            t7_ = *reinterpret_cast<const s16x8*>(xr_ + (2 * XH + 1) * 64); \
            t8_ = *reinterpret_cast<const s16x8*>(xr_ + (2 * XH + 2) * 64); \
        } while (0)

        ISSUE(0);
        #pragma unroll 1
        for (int it = 0; it < niter; ++it) {
            const int t = it * 4 + sg;
            const bool live = (t < ntile);
            if (live) {
                *reinterpret_cast<s16x8*>(arow + 0 * 64) = t0_;
                *reinterpret_cast<s16x8*>(arow + 1 * 64) = t1_;
                *reinterpret_cast<s16x8*>(arow + 2 * 64) = t2_;
                *reinterpret_cast<s16x8*>(arow + 3 * 64) = t3_;
                *reinterpret_cast<s16x8*>(arow + 4 * 64) = t4_;
                *reinterpret_cast<s16x8*>(arow + 5 * 64) = t5_;
                *reinterpret_cast<s16x8*>(arow + 6 * 64) = t6_;
                *reinterpret_cast<s16x8*>(arow + 7 * 64) = t7_;
                *reinterpret_cast<s16x8*>(arow + 8 * 64) = t8_;
            }
            __syncthreads();
            if (it + 1 < niter) ISSUE(it + 1);   // issue early; write next iter
            if (live) {
                f32x4 acc0 = {0.f, 0.f, 0.f, 0.f}, acc1 = {0.f, 0.f, 0.f, 0.f};
                const unsigned short* ar0 = albuf + l16 * 584 + quad * 8;
                const unsigned short* ar1 = ar0 + 16 * 584;
                #pragma unroll
                for (int ks = 0; ks < 18; ++ks) {
                    s16x8 a0 = *reinterpret_cast<const s16x8*>(ar0 + ks * 32);
                    s16x8 a1 = *reinterpret_cast<const s16x8*>(ar1 + ks * 32);
                    acc0 = __builtin_amdgcn_mfma_f32_16x16x32_bf16(a0, bfr[ks], acc0, 0, 0, 0);
                    acc1 = __builtin_amdgcn_mfma_f32_16x16x32_bf16(a1, bfr[ks], acc1, 0, 0, 0);
                }
                #pragma unroll
                for (int r = 0; r < 4; ++r) {
                    int s0 = (t << 5) + quad * 4 + r;
                    if (s0 < cnt)
                        ob[(size_t)(s0 * 16 + k) * 64 + col] = f2bf(acc0[r] + bb);
                    int s1 = s0 + 16;
                    if (s1 < cnt)
                        ob[(size_t)(s1 * 16 + k) * 64 + col] = f2bf(acc1[r] + bb);
                }
            }
            __syncthreads();
        }
        #undef ISSUE
    }
}

// ---------------------------------------------------------------------------
// k_scatter (R6): grid 1024. Interleaved outc: row = slotmap[n]*16 + lab[n],
// no prefix/counts needed. 16B gathers, LDS transpose (rows padded to 20
// u16), coalesced f32 stores.
// ---------------------------------------------------------------------------
extern "C" __global__ __launch_bounds__(256)
void k_scatter(const int* __restrict__ labels, const unsigned short* __restrict__ slotmap,
               const unsigned short* __restrict__ outc, float* __restrict__ out)
{
    const int blk = blockIdx.x;
    const int b = blk & 15, chunk = (blk >> 4) & 15, q = blk >> 8;
    const int tid = threadIdx.x;
    __shared__ int sptr[256];
    __shared__ unsigned short tt[256 * 20];     // 10 KB
    const int n0 = chunk * 256;
    {
        int n = n0 + tid;
        sptr[tid] = (int)slotmap[b * NPIX + n] * 16 + labels[b * NPIX + n];
    }
    __syncthreads();
    #pragma unroll
    for (int e0 = 0; e0 < 2; ++e0) {
        int e = e0 * 256 + tid;
        int pix = e >> 1, part = e & 1;
        s16x8 vv = *reinterpret_cast<const s16x8*>(
            outc + ((size_t)b * (OROWS * 64)) + (size_t)sptr[pix] * 64 + q * 16 + part * 8);
        s16x4 lo = {vv[0], vv[1], vv[2], vv[3]};
        s16x4 hi = {vv[4], vv[5], vv[6], vv[7]};
        *reinterpret_cast<s16x4*>(tt + pix * 20 + part * 8) = lo;
        *reinterpret_cast<s16x4*>(tt + pix * 20 + part * 8 + 4) = hi;
    }
    __syncthreads();
    float* ob = out + ((size_t)(b * NOUT + q * 16)) * NPIX + n0;
    #pragma unroll
    for (int oo = 0; oo < 16; ++oo)
        ob[(size_t)oo * NPIX + tid] = bf2f(tt[tid * 20 + oo]);
}

// ---------------------------------------------------------------------------
// Workspace layout (total used 26,419,200 of 39,068,672 B):
//   basekF  @ 0        : 589,824
//   slotmap @ 589824   : 131,072
//   xcl     @ 720896   : 8,921,088
//   outc    @ 9641984  : 16,777,216   (16 images x 8192 interleaved rows x 64)
// ---------------------------------------------------------------------------
extern "C" void kernel_launch(void* const* d_in, const int* in_sizes, int n_in,
                              void* d_out, int out_size, void* d_ws, size_t ws_size,
                              hipStream_t stream)
{
    const float* x      = (const float*)d_in[0];
    const int*   labels = (const int*)d_in[1];
    const float* lw1    = (const float*)d_in[2];
    const float* lb1    = (const float*)d_in[3];
    const float* lw2    = (const float*)d_in[4];
    const float* lb2    = (const float*)d_in[5];
    const float* lw3    = (const float*)d_in[6];
    const float* lb3    = (const float*)d_in[7];
    const float* basek  = (const float*)d_in[8];
    const float* bw1    = (const float*)d_in[9];
    const float* bb1    = (const float*)d_in[10];
    const float* bw2    = (const float*)d_in[11];
    const float* bb2    = (const float*)d_in[12];
    float* out = (float*)d_out;

    char* ws = (char*)d_ws;
    unsigned short* basekF  = (unsigned short*)(ws);
    unsigned short* slotmap = (unsigned short*)(ws + 589824);
    unsigned short* xcl     = (unsigned short*)(ws + 720896);
    unsigned short* outc    = (unsigned short*)(ws + 9641984);

    k_prep_all<<<XH * 16 + 72, 256, 0, stream>>>(x, basek, xcl, basekF);
    k_cm<<<256, 1024, 157952, stream>>>(xcl, labels, lw1, lb1, lw2, lb2, lw3, lb3,
                                        bw1, bb1, bw2, bb2, basekF, slotmap, outc);
    k_scatter<<<1024, 256, 0, stream>>>(labels, slotmap, outc, out);
}

// Round 11
// 125.757 us; speedup vs baseline: 1.0372x; 1.0372x over previous
//
#include <hip/hip_runtime.h>
#include <stdint.h>
#include <stddef.h>

// Problem constants
#define NB   16
#define NC   64
#define NH   64
#define NW   64
#define KC   16
#define NOUT 64
#define NRANK 8
#define NMLP 32
#define NF   576      // C*3*3
#define NPIX 4096     // H*W
#define XH   66       // halo height/width for channel-last copy
#define OROWS 8192    // interleaved outc rows per image (row = slot*16 + k)

typedef short s16x8 __attribute__((ext_vector_type(8)));
typedef short s16x4 __attribute__((ext_vector_type(4)));
typedef float f32x4 __attribute__((ext_vector_type(4)));

__device__ __forceinline__ unsigned short f2bf(float x) {
    union { float f; uint32_t u; } v; v.f = x;
    uint32_t r = v.u + 0x7FFFu + ((v.u >> 16) & 1u);   // RTNE
    return (unsigned short)(r >> 16);
}
__device__ __forceinline__ float bf2f(unsigned short u) {
    union { uint32_t u; float f; } v; v.u = ((uint32_t)u) << 16;
    return v.f;
}

// ---------------------------------------------------------------------------
// k_prep_all (R0 exact): blocks [0,1056): xcl; [1056,1128): basekF.
// ---------------------------------------------------------------------------
extern "C" __global__ __launch_bounds__(256)
void k_prep_all(const float* __restrict__ x, const float* __restrict__ basek,
                unsigned short* __restrict__ xcl, unsigned short* __restrict__ basekF)
{
    __shared__ float tile[64 * 65];
    const int blk0 = blockIdx.x;
    const int tid = threadIdx.x;
    if (blk0 < XH * 16) {
        const int b = blk0 & 15, yy = blk0 >> 4;
        unsigned short* dst = xcl + ((size_t)(b * XH + yy) * XH) * 64;
        if (yy == 0 || yy == XH - 1) {
            for (int e = tid; e < XH * 64; e += 256) dst[e] = 0;
            return;
        }
        const int y = yy - 1;
        const float* src = x + (size_t)b * NC * (NH * NW) + y * NW;
        #pragma unroll
        for (int rr = 0; rr < 16; ++rr) {
            int c = rr * 4 + (tid >> 6);
            int xx = tid & 63;
            tile[c * 65 + xx] = src[(size_t)c * (NH * NW) + xx];
        }
        __syncthreads();
        for (int ee = tid; ee < 528; ee += 256) {
            int xx = ee >> 3;
            int c0 = (ee & 7) * 8;
            s16x8 v;
            #pragma unroll
            for (int j = 0; j < 8; ++j) {
                float f = (xx == 0 || xx == XH - 1) ? 0.f : tile[(c0 + j) * 65 + (xx - 1)];
                v[j] = (short)f2bf(f);
            }
            *reinterpret_cast<s16x8*>(dst + ee * 8) = v;
        }
    } else {
        const int blk = blk0 - XH * 16;    // ks*4 + wv
        const int ks = blk >> 2, wv = blk & 3;
        unsigned short outv[16];
        #pragma unroll
        for (int i = 0; i < 16; ++i) {
            int e = tid * 16 + i;          // e = r*512 + lane*8 + j
            int r = e >> 9;
            int lane = (e >> 3) & 63;
            int j = e & 7;
            int col = wv * 16 + (lane & 15);
            int fp = (lane >> 4) * 8 + ks * 32 + j;
            int tap = fp >> 6, c = fp & 63;
            outv[i] = f2bf(basek[((size_t)r * NF + c * 9 + tap) * NOUT + col]);
        }
        unsigned short* dst = basekF + (size_t)blk * 4096 + tid * 16;
        #pragma unroll
        for (int i = 0; i < 16; ++i) dst[i] = outv[i];
    }
}

// ---------------------------------------------------------------------------
// k_cm (R10): fused centers+main, one block per (b,k), 1024 threads.
// R10 = R8's GEMM staging (verbatim; R9's async-STAGE reverted — suspected
// regressor) + R9's widened MLP layer-1 (kept; mechanism-safe).
// Dynamic LDS 157,952 B:
//   list @0 (8192, live all phases) | wcnt @8192 | wsum @8256 (36864)
//   cbuf @45120 (2304) | h1/h2/hb/lrs @49472..49888
//   p1 @51200 (4096), pb @55296 (4096)  [overlap Wl; dead before W-exp]
//   Wl @51200 (73728, dead after bfr load) | albuf @8192+sg*37376 (x4)
//   biasl @157696 (256)
// ---------------------------------------------------------------------------
extern "C" __global__ __launch_bounds__(1024, 1)
void k_cm(const unsigned short* __restrict__ xcl, const int* __restrict__ labels,
          const float* __restrict__ lw1, const float* __restrict__ lb1,
          const float* __restrict__ lw2, const float* __restrict__ lb2,
          const float* __restrict__ lw3, const float* __restrict__ lb3,
          const float* __restrict__ bw1, const float* __restrict__ bb1,
          const float* __restrict__ bw2, const float* __restrict__ bb2,
          const unsigned short* __restrict__ basekF,
          unsigned short* __restrict__ slotmap, unsigned short* __restrict__ outc)
{
    extern __shared__ __align__(16) char smem[];
    unsigned short* list = (unsigned short*)smem;
    int*   wcnt  = (int*)(smem + 8192);
    float* wsum  = (float*)(smem + 8256);
    float* cbuf  = (float*)(smem + 45120);
    float* h1    = (float*)(smem + 49472);
    float* h2    = (float*)(smem + 49600);
    float* hb    = (float*)(smem + 49728);
    float* lrs   = (float*)(smem + 49856);
    float* p1    = (float*)(smem + 51200);   // 32*32*4, overlaps Wl (dead later)
    float* pb    = (float*)(smem + 55296);   // 32*32*4
    unsigned short* Wl = (unsigned short*)(smem + 51200);
    float* biasl = (float*)(smem + 157696);

    const int bk = blockIdx.x;
    const int b = bk & 15, k = bk >> 4;
    const int tid = threadIdx.x;
    const int lane = tid & 63, wv = tid >> 6;    // wv 0..15
    const int st = tid & 255, sg = tid >> 8;     // 4 sub-groups of 256
    const int* lab = labels + b * NPIX;

    // ---- unordered single-atomic compaction (R8)
    if (tid == 0) wcnt[0] = 0;
    __syncthreads();
    {
        const int n0 = tid, n1 = 1024 + tid, n2 = 2048 + tid, n3 = 3072 + tid;
        const int l0 = lab[n0], l1 = lab[n1], l2 = lab[n2], l3 = lab[n3];
        const bool q0 = (l0 == k), q1 = (l1 == k), q2 = (l2 == k), q3 = (l3 == k);
        const unsigned long long m0 = __ballot(q0), m1 = __ballot(q1),
                                 m2 = __ballot(q2), m3 = __ballot(q3);
        const int c0 = __popcll(m0), c1 = __popcll(m1),
                  c2 = __popcll(m2), c3 = __popcll(m3);
        int base = 0;
        if (lane == 0)
            base = __hip_atomic_fetch_add(&wcnt[0], c0 + c1 + c2 + c3,
                                          __ATOMIC_RELAXED, __HIP_MEMORY_SCOPE_WORKGROUP);
        base = __shfl(base, 0);
        const unsigned long long lt = (1ull << lane) - 1ull;
        if (q0) { int s = base + __popcll(m0 & lt);
                  list[s] = (unsigned short)n0; slotmap[b * NPIX + n0] = (unsigned short)s; }
        base += c0;
        if (q1) { int s = base + __popcll(m1 & lt);
                  list[s] = (unsigned short)n1; slotmap[b * NPIX + n1] = (unsigned short)s; }
        base += c1;
        if (q2) { int s = base + __popcll(m2 & lt);
                  list[s] = (unsigned short)n2; slotmap[b * NPIX + n2] = (unsigned short)s; }
        base += c2;
        if (q3) { int s = base + __popcll(m3 & lt);
                  list[s] = (unsigned short)n3; slotmap[b * NPIX + n3] = (unsigned short)s; }
    }
    __syncthreads();
    const int cnt = wcnt[0];

    // ---- gather: wave wv handles pixels i = wv, wv+16, ...; lane = channel
    float s00 = 0.f, s01 = 0.f, s02 = 0.f,
          s10 = 0.f, s11 = 0.f, s12 = 0.f,
          s20 = 0.f, s21 = 0.f, s22 = 0.f;
    const unsigned short* xb0 = xcl + (size_t)b * (XH * XH * 64) + lane;
    #pragma unroll 4
    for (int i = wv; i < cnt; i += 16) {
        int n = list[i];
        const unsigned short* p0 = xb0 + (((n >> 6) * XH) + (n & 63)) * 64;
        s00 += bf2f(p0[0]);
        s01 += bf2f(p0[64]);
        s02 += bf2f(p0[128]);
        const unsigned short* prow1 = p0 + XH * 64;
        s10 += bf2f(prow1[0]);
        s11 += bf2f(prow1[64]);
        s12 += bf2f(prow1[128]);
        const unsigned short* prow2 = p0 + 2 * XH * 64;
        s20 += bf2f(prow2[0]);
        s21 += bf2f(prow2[64]);
        s22 += bf2f(prow2[128]);
    }
    {
        float* wrow = wsum + wv * 576 + lane;
        wrow[0 * 64] = s00; wrow[1 * 64] = s01; wrow[2 * 64] = s02;
        wrow[3 * 64] = s10; wrow[4 * 64] = s11; wrow[5 * 64] = s12;
        wrow[6 * 64] = s20; wrow[7 * 64] = s21; wrow[8 * 64] = s22;
    }
    __syncthreads();

    // ---- reduce 16 waves -> centers (feature order c*9+tap)
    const float inv = 1.f / ((float)cnt + 1e-6f);
    if (tid < NF) {
        int tap = tid >> 6, c = tid & 63;
        float s = 0.f;
        #pragma unroll
        for (int w = 0; w < 16; ++w) s += wsum[w * 576 + tap * 64 + c];
        cbuf[c * 9 + tap] = s * inv;
    }
    __syncthreads();

    // ---- fused MLPs (layer-1 widened: 1024 threads, 32 chunks x 18 feats)
    {
        const int j = tid & 31, ch = tid >> 5;       // ch 0..31
        float a1 = 0.f, a2 = 0.f;
        #pragma unroll
        for (int i = 0; i < 18; ++i) {
            int f = ch * 18 + i;
            float cv = cbuf[f];
            a1 += cv * lw1[f * NMLP + j];
            a2 += cv * bw1[f * NMLP + j];
        }
        p1[ch * NMLP + j] = a1; pb[ch * NMLP + j] = a2;
    }
    __syncthreads();
    if (tid < NMLP) {
        float a = lb1[tid];
        #pragma unroll
        for (int i = 0; i < 32; ++i) a += p1[i * NMLP + tid];
        h1[tid] = fmaxf(a, 0.f);
    } else if (tid < 2 * NMLP) {
        int j = tid - NMLP;
        float a = bb1[j];
        #pragma unroll
        for (int i = 0; i < 32; ++i) a += pb[i * NMLP + j];
        hb[j] = fmaxf(a, 0.f);
    }
    __syncthreads();
    if (tid < NMLP) {
        float a = lb2[tid];
        for (int i = 0; i < NMLP; ++i) a += h1[i] * lw2[i * NMLP + tid];
        h2[tid] = fmaxf(a, 0.f);
    } else if (tid >= 64 && tid < 128) {
        int o = tid - 64;
        float a = bb2[o];
        for (int i = 0; i < NMLP; ++i) a += hb[i] * bw2[i * NOUT + o];
        biasl[o] = a;                           // LDS, not global
    }
    __syncthreads();
    if (tid < NRANK) {
        float a = lb3[tid];
        for (int i = 0; i < NMLP; ++i) a += h2[i] * lw3[i * NRANK + tid];
        lrs[tid] = a;
    }
    __syncthreads();

    // ---- W-expansion into LDS Wl (R13-proven math, identical rounding)
    {
        float l8[NRANK];
        #pragma unroll
        for (int r = 0; r < NRANK; ++r) l8[r] = lrs[r];
        #pragma unroll 2
        for (int q = 0; q < 5; ++q) {
            int m = q * 1024 + tid;            // 0..4607 valid
            if (m < 4608) {
                int ks = m >> 8, t = m & 255;
                const unsigned short* src = basekF
                    + ((size_t)(ks * 4 + (t >> 6)) * 8) * 512 + (t & 63) * 8;
                float w[8] = {0.f, 0.f, 0.f, 0.f, 0.f, 0.f, 0.f, 0.f};
                #pragma unroll
                for (int r = 0; r < NRANK; ++r) {
                    s16x8 bv = *reinterpret_cast<const s16x8*>(src + r * 512);
                    #pragma unroll
                    for (int j = 0; j < 8; ++j)
                        w[j] += l8[r] * bf2f((unsigned short)bv[j]);
                }
                s16x8 f;
                #pragma unroll
                for (int j = 0; j < 8; ++j) f[j] = (short)f2bf(w[j]);
                *reinterpret_cast<s16x8*>(Wl + m * 8) = f;
            }
        }
    }
    __syncthreads();

    // ---- load B-fragments from Wl into registers, then free Wl for albufs
    s16x8 bfr[18];
    #pragma unroll
    for (int ks = 0; ks < 18; ++ks)
        bfr[ks] = *reinterpret_cast<const s16x8*>(Wl + ks * 2048 + st * 8);
    __syncthreads();

    // ---- main GEMM (R8 verbatim: R12 tiling, 4 sub-groups, simple staging;
    //      output rows interleaved)
    {
        const int wv4 = (tid >> 6) & 3;
        const int quad = lane >> 4, l16 = lane & 15;
        unsigned short* albuf = (unsigned short*)(smem + 8192 + sg * 37376);
        const int col = wv4 * 16 + l16;
        const float bb = biasl[col];
        const unsigned short* xb = xcl + (size_t)b * (XH * XH * 64);
        const int p = st >> 3, part = st & 7;
        const int ntile = (cnt + 31) >> 5;
        const int niter = (ntile + 3) >> 2;
        unsigned short* ob = outc + (size_t)b * (OROWS * 64);

        #pragma unroll 1
        for (int it = 0; it < niter; ++it) {
            const int t = it * 4 + sg;
            const bool live = (t < ntile);
            if (live) {
                int slot = (t << 5) + p;
                int n = (slot < cnt) ? (int)list[slot] : 0;
                const unsigned short* xrow =
                    xb + (((n >> 6) * XH) + (n & 63)) * 64 + part * 8;
                unsigned short* arow = albuf + p * 584 + part * 8;
                #pragma unroll
                for (int tap = 0; tap < 9; ++tap) {
                    int dy = tap / 3, dx = tap - dy * 3;
                    *reinterpret_cast<s16x8*>(arow + tap * 64) =
                        *reinterpret_cast<const s16x8*>(xrow + (dy * XH + dx) * 64);
                }
            }
            __syncthreads();
            if (live) {
                f32x4 acc0 = {0.f, 0.f, 0.f, 0.f}, acc1 = {0.f, 0.f, 0.f, 0.f};
                const unsigned short* ar0 = albuf + l16 * 584 + quad * 8;
                const unsigned short* ar1 = ar0 + 16 * 584;
                #pragma unroll
                for (int ks = 0; ks < 18; ++ks) {
                    s16x8 a0 = *reinterpret_cast<const s16x8*>(ar0 + ks * 32);
                    s16x8 a1 = *reinterpret_cast<const s16x8*>(ar1 + ks * 32);
                    acc0 = __builtin_amdgcn_mfma_f32_16x16x32_bf16(a0, bfr[ks], acc0, 0, 0, 0);
                    acc1 = __builtin_amdgcn_mfma_f32_16x16x32_bf16(a1, bfr[ks], acc1, 0, 0, 0);
                }
                #pragma unroll
                for (int r = 0; r < 4; ++r) {
                    int s0 = (t << 5) + quad * 4 + r;
                    if (s0 < cnt)
                        ob[(size_t)(s0 * 16 + k) * 64 + col] = f2bf(acc0[r] + bb);
                    int s1 = s0 + 16;
                    if (s1 < cnt)
                        ob[(size_t)(s1 * 16 + k) * 64 + col] = f2bf(acc1[r] + bb);
                }
            }
            __syncthreads();
        }
    }
}

// ---------------------------------------------------------------------------
// k_scatter (R6): grid 1024. Interleaved outc: row = slotmap[n]*16 + lab[n],
// no prefix/counts needed. 16B gathers, LDS transpose (rows padded to 20
// u16), coalesced f32 stores.
// ---------------------------------------------------------------------------
extern "C" __global__ __launch_bounds__(256)
void k_scatter(const int* __restrict__ labels, const unsigned short* __restrict__ slotmap,
               const unsigned short* __restrict__ outc, float* __restrict__ out)
{
    const int blk = blockIdx.x;
    const int b = blk & 15, chunk = (blk >> 4) & 15, q = blk >> 8;
    const int tid = threadIdx.x;
    __shared__ int sptr[256];
    __shared__ unsigned short tt[256 * 20];     // 10 KB
    const int n0 = chunk * 256;
    {
        int n = n0 + tid;
        sptr[tid] = (int)slotmap[b * NPIX + n] * 16 + labels[b * NPIX + n];
    }
    __syncthreads();
    #pragma unroll
    for (int e0 = 0; e0 < 2; ++e0) {
        int e = e0 * 256 + tid;
        int pix = e >> 1, part = e & 1;
        s16x8 vv = *reinterpret_cast<const s16x8*>(
            outc + ((size_t)b * (OROWS * 64)) + (size_t)sptr[pix] * 64 + q * 16 + part * 8);
        s16x4 lo = {vv[0], vv[1], vv[2], vv[3]};
        s16x4 hi = {vv[4], vv[5], vv[6], vv[7]};
        *reinterpret_cast<s16x4*>(tt + pix * 20 + part * 8) = lo;
        *reinterpret_cast<s16x4*>(tt + pix * 20 + part * 8 + 4) = hi;
    }
    __syncthreads();
    float* ob = out + ((size_t)(b * NOUT + q * 16)) * NPIX + n0;
    #pragma unroll
    for (int oo = 0; oo < 16; ++oo)
        ob[(size_t)oo * NPIX + tid] = bf2f(tt[tid * 20 + oo]);
}

// ---------------------------------------------------------------------------
// Workspace layout (total used 26,419,200 of 39,068,672 B):
//   basekF  @ 0        : 589,824
//   slotmap @ 589824   : 131,072
//   xcl     @ 720896   : 8,921,088
//   outc    @ 9641984  : 16,777,216   (16 images x 8192 interleaved rows x 64)
// ---------------------------------------------------------------------------
extern "C" void kernel_launch(void* const* d_in, const int* in_sizes, int n_in,
                              void* d_out, int out_size, void* d_ws, size_t ws_size,
                              hipStream_t stream)
{
    const float* x      = (const float*)d_in[0];
    const int*   labels = (const int*)d_in[1];
    const float* lw1    = (const float*)d_in[2];
    const float* lb1    = (const float*)d_in[3];
    const float* lw2    = (const float*)d_in[4];
    const float* lb2    = (const float*)d_in[5];
    const float* lw3    = (const float*)d_in[6];
    const float* lb3    = (const float*)d_in[7];
    const float* basek  = (const float*)d_in[8];
    const float* bw1    = (const float*)d_in[9];
    const float* bb1    = (const float*)d_in[10];
    const float* bw2    = (const float*)d_in[11];
    const float* bb2    = (const float*)d_in[12];
    float* out = (float*)d_out;

    char* ws = (char*)d_ws;
    unsigned short* basekF  = (unsigned short*)(ws);
    unsigned short* slotmap = (unsigned short*)(ws + 589824);
    unsigned short* xcl     = (unsigned short*)(ws + 720896);
    unsigned short* outc    = (unsigned short*)(ws + 9641984);

    k_prep_all<<<XH * 16 + 72, 256, 0, stream>>>(x, basek, xcl, basekF);
    k_cm<<<256, 1024, 157952, stream>>>(xcl, labels, lw1, lb1, lw2, lb2, lw3, lb3,
                                        bw1, bb1, bw2, bb2, basekF, slotmap, outc);
    k_scatter<<<1024, 256, 0, stream>>>(labels, slotmap, outc, out);
}

// Round 12
// 125.129 us; speedup vs baseline: 1.0424x; 1.0050x over previous
//
#include <hip/hip_runtime.h>
#include <stdint.h>
#include <stddef.h>

// Problem constants
#define NB   16
#define NC   64
#define NH   64
#define NW   64
#define KC   16
#define NOUT 64
#define NRANK 8
#define NMLP 32
#define NF   576      // C*3*3
#define NPIX 4096     // H*W
#define XH   66       // halo height/width for channel-last copy
#define OROWS 8192    // interleaved outc rows per image (row = slot*16 + k)

typedef short s16x8 __attribute__((ext_vector_type(8)));
typedef short s16x4 __attribute__((ext_vector_type(4)));
typedef float f32x4 __attribute__((ext_vector_type(4)));

__device__ __forceinline__ unsigned short f2bf(float x) {
    union { float f; uint32_t u; } v; v.f = x;
    uint32_t r = v.u + 0x7FFFu + ((v.u >> 16) & 1u);   // RTNE
    return (unsigned short)(r >> 16);
}
__device__ __forceinline__ float bf2f(unsigned short u) {
    union { uint32_t u; float f; } v; v.u = ((uint32_t)u) << 16;
    return v.f;
}

// ---------------------------------------------------------------------------
// k_prep_all (R0 exact): blocks [0,1056): xcl; [1056,1128): basekF.
// ---------------------------------------------------------------------------
extern "C" __global__ __launch_bounds__(256)
void k_prep_all(const float* __restrict__ x, const float* __restrict__ basek,
                unsigned short* __restrict__ xcl, unsigned short* __restrict__ basekF)
{
    __shared__ float tile[64 * 65];
    const int blk0 = blockIdx.x;
    const int tid = threadIdx.x;
    if (blk0 < XH * 16) {
        const int b = blk0 & 15, yy = blk0 >> 4;
        unsigned short* dst = xcl + ((size_t)(b * XH + yy) * XH) * 64;
        if (yy == 0 || yy == XH - 1) {
            for (int e = tid; e < XH * 64; e += 256) dst[e] = 0;
            return;
        }
        const int y = yy - 1;
        const float* src = x + (size_t)b * NC * (NH * NW) + y * NW;
        #pragma unroll
        for (int rr = 0; rr < 16; ++rr) {
            int c = rr * 4 + (tid >> 6);
            int xx = tid & 63;
            tile[c * 65 + xx] = src[(size_t)c * (NH * NW) + xx];
        }
        __syncthreads();
        for (int ee = tid; ee < 528; ee += 256) {
            int xx = ee >> 3;
            int c0 = (ee & 7) * 8;
            s16x8 v;
            #pragma unroll
            for (int j = 0; j < 8; ++j) {
                float f = (xx == 0 || xx == XH - 1) ? 0.f : tile[(c0 + j) * 65 + (xx - 1)];
                v[j] = (short)f2bf(f);
            }
            *reinterpret_cast<s16x8*>(dst + ee * 8) = v;
        }
    } else {
        const int blk = blk0 - XH * 16;    // ks*4 + wv
        const int ks = blk >> 2, wv = blk & 3;
        unsigned short outv[16];
        #pragma unroll
        for (int i = 0; i < 16; ++i) {
            int e = tid * 16 + i;          // e = r*512 + lane*8 + j
            int r = e >> 9;
            int lane = (e >> 3) & 63;
            int j = e & 7;
            int col = wv * 16 + (lane & 15);
            int fp = (lane >> 4) * 8 + ks * 32 + j;
            int tap = fp >> 6, c = fp & 63;
            outv[i] = f2bf(basek[((size_t)r * NF + c * 9 + tap) * NOUT + col]);
        }
        unsigned short* dst = basekF + (size_t)blk * 4096 + tid * 16;
        #pragma unroll
        for (int i = 0; i < 16; ++i) dst[i] = outv[i];
    }
}

// ---------------------------------------------------------------------------
// k_cm (R12): fused centers+main, one block per (b,k), 1024 threads.
// R12 changes vs R10 (both independent, mechanism-clear):
//  - gather unroll 4 -> 8 (2 latency chain-steps instead of 4; VGPRs free at
//    1 block/CU).
//  - trailing GEMM barrier dropped (post-MFMA barrier only protects albuf
//    reuse by the NEXT iteration; skip on last).
// Dynamic LDS 157,952 B (layout unchanged from R10).
// ---------------------------------------------------------------------------
extern "C" __global__ __launch_bounds__(1024, 1)
void k_cm(const unsigned short* __restrict__ xcl, const int* __restrict__ labels,
          const float* __restrict__ lw1, const float* __restrict__ lb1,
          const float* __restrict__ lw2, const float* __restrict__ lb2,
          const float* __restrict__ lw3, const float* __restrict__ lb3,
          const float* __restrict__ bw1, const float* __restrict__ bb1,
          const float* __restrict__ bw2, const float* __restrict__ bb2,
          const unsigned short* __restrict__ basekF,
          unsigned short* __restrict__ slotmap, unsigned short* __restrict__ outc)
{
    extern __shared__ __align__(16) char smem[];
    unsigned short* list = (unsigned short*)smem;
    int*   wcnt  = (int*)(smem + 8192);
    float* wsum  = (float*)(smem + 8256);
    float* cbuf  = (float*)(smem + 45120);
    float* h1    = (float*)(smem + 49472);
    float* h2    = (float*)(smem + 49600);
    float* hb    = (float*)(smem + 49728);
    float* lrs   = (float*)(smem + 49856);
    float* p1    = (float*)(smem + 51200);   // 32*32*4, overlaps Wl (dead later)
    float* pb    = (float*)(smem + 55296);   // 32*32*4
    unsigned short* Wl = (unsigned short*)(smem + 51200);
    float* biasl = (float*)(smem + 157696);

    const int bk = blockIdx.x;
    const int b = bk & 15, k = bk >> 4;
    const int tid = threadIdx.x;
    const int lane = tid & 63, wv = tid >> 6;    // wv 0..15
    const int st = tid & 255, sg = tid >> 8;     // 4 sub-groups of 256
    const int* lab = labels + b * NPIX;

    // ---- unordered single-atomic compaction (R8)
    if (tid == 0) wcnt[0] = 0;
    __syncthreads();
    {
        const int n0 = tid, n1 = 1024 + tid, n2 = 2048 + tid, n3 = 3072 + tid;
        const int l0 = lab[n0], l1 = lab[n1], l2 = lab[n2], l3 = lab[n3];
        const bool q0 = (l0 == k), q1 = (l1 == k), q2 = (l2 == k), q3 = (l3 == k);
        const unsigned long long m0 = __ballot(q0), m1 = __ballot(q1),
                                 m2 = __ballot(q2), m3 = __ballot(q3);
        const int c0 = __popcll(m0), c1 = __popcll(m1),
                  c2 = __popcll(m2), c3 = __popcll(m3);
        int base = 0;
        if (lane == 0)
            base = __hip_atomic_fetch_add(&wcnt[0], c0 + c1 + c2 + c3,
                                          __ATOMIC_RELAXED, __HIP_MEMORY_SCOPE_WORKGROUP);
        base = __shfl(base, 0);
        const unsigned long long lt = (1ull << lane) - 1ull;
        if (q0) { int s = base + __popcll(m0 & lt);
                  list[s] = (unsigned short)n0; slotmap[b * NPIX + n0] = (unsigned short)s; }
        base += c0;
        if (q1) { int s = base + __popcll(m1 & lt);
                  list[s] = (unsigned short)n1; slotmap[b * NPIX + n1] = (unsigned short)s; }
        base += c1;
        if (q2) { int s = base + __popcll(m2 & lt);
                  list[s] = (unsigned short)n2; slotmap[b * NPIX + n2] = (unsigned short)s; }
        base += c2;
        if (q3) { int s = base + __popcll(m3 & lt);
                  list[s] = (unsigned short)n3; slotmap[b * NPIX + n3] = (unsigned short)s; }
    }
    __syncthreads();
    const int cnt = wcnt[0];

    // ---- gather: wave wv handles pixels i = wv, wv+16, ...; lane = channel
    float s00 = 0.f, s01 = 0.f, s02 = 0.f,
          s10 = 0.f, s11 = 0.f, s12 = 0.f,
          s20 = 0.f, s21 = 0.f, s22 = 0.f;
    const unsigned short* xb0 = xcl + (size_t)b * (XH * XH * 64) + lane;
    #pragma unroll 8
    for (int i = wv; i < cnt; i += 16) {
        int n = list[i];
        const unsigned short* p0 = xb0 + (((n >> 6) * XH) + (n & 63)) * 64;
        s00 += bf2f(p0[0]);
        s01 += bf2f(p0[64]);
        s02 += bf2f(p0[128]);
        const unsigned short* prow1 = p0 + XH * 64;
        s10 += bf2f(prow1[0]);
        s11 += bf2f(prow1[64]);
        s12 += bf2f(prow1[128]);
        const unsigned short* prow2 = p0 + 2 * XH * 64;
        s20 += bf2f(prow2[0]);
        s21 += bf2f(prow2[64]);
        s22 += bf2f(prow2[128]);
    }
    {
        float* wrow = wsum + wv * 576 + lane;
        wrow[0 * 64] = s00; wrow[1 * 64] = s01; wrow[2 * 64] = s02;
        wrow[3 * 64] = s10; wrow[4 * 64] = s11; wrow[5 * 64] = s12;
        wrow[6 * 64] = s20; wrow[7 * 64] = s21; wrow[8 * 64] = s22;
    }
    __syncthreads();

    // ---- reduce 16 waves -> centers (feature order c*9+tap)
    const float inv = 1.f / ((float)cnt + 1e-6f);
    if (tid < NF) {
        int tap = tid >> 6, c = tid & 63;
        float s = 0.f;
        #pragma unroll
        for (int w = 0; w < 16; ++w) s += wsum[w * 576 + tap * 64 + c];
        cbuf[c * 9 + tap] = s * inv;
    }
    __syncthreads();

    // ---- fused MLPs (layer-1 widened: 1024 threads, 32 chunks x 18 feats)
    {
        const int j = tid & 31, ch = tid >> 5;       // ch 0..31
        float a1 = 0.f, a2 = 0.f;
        #pragma unroll
        for (int i = 0; i < 18; ++i) {
            int f = ch * 18 + i;
            float cv = cbuf[f];
            a1 += cv * lw1[f * NMLP + j];
            a2 += cv * bw1[f * NMLP + j];
        }
        p1[ch * NMLP + j] = a1; pb[ch * NMLP + j] = a2;
    }
    __syncthreads();
    if (tid < NMLP) {
        float a = lb1[tid];
        #pragma unroll
        for (int i = 0; i < 32; ++i) a += p1[i * NMLP + tid];
        h1[tid] = fmaxf(a, 0.f);
    } else if (tid < 2 * NMLP) {
        int j = tid - NMLP;
        float a = bb1[j];
        #pragma unroll
        for (int i = 0; i < 32; ++i) a += pb[i * NMLP + j];
        hb[j] = fmaxf(a, 0.f);
    }
    __syncthreads();
    if (tid < NMLP) {
        float a = lb2[tid];
        for (int i = 0; i < NMLP; ++i) a += h1[i] * lw2[i * NMLP + tid];
        h2[tid] = fmaxf(a, 0.f);
    } else if (tid >= 64 && tid < 128) {
        int o = tid - 64;
        float a = bb2[o];
        for (int i = 0; i < NMLP; ++i) a += hb[i] * bw2[i * NOUT + o];
        biasl[o] = a;                           // LDS, not global
    }
    __syncthreads();
    if (tid < NRANK) {
        float a = lb3[tid];
        for (int i = 0; i < NMLP; ++i) a += h2[i] * lw3[i * NRANK + tid];
        lrs[tid] = a;
    }
    __syncthreads();

    // ---- W-expansion into LDS Wl (R13-proven math, identical rounding)
    {
        float l8[NRANK];
        #pragma unroll
        for (int r = 0; r < NRANK; ++r) l8[r] = lrs[r];
        #pragma unroll 2
        for (int q = 0; q < 5; ++q) {
            int m = q * 1024 + tid;            // 0..4607 valid
            if (m < 4608) {
                int ks = m >> 8, t = m & 255;
                const unsigned short* src = basekF
                    + ((size_t)(ks * 4 + (t >> 6)) * 8) * 512 + (t & 63) * 8;
                float w[8] = {0.f, 0.f, 0.f, 0.f, 0.f, 0.f, 0.f, 0.f};
                #pragma unroll
                for (int r = 0; r < NRANK; ++r) {
                    s16x8 bv = *reinterpret_cast<const s16x8*>(src + r * 512);
                    #pragma unroll
                    for (int j = 0; j < 8; ++j)
                        w[j] += l8[r] * bf2f((unsigned short)bv[j]);
                }
                s16x8 f;
                #pragma unroll
                for (int j = 0; j < 8; ++j) f[j] = (short)f2bf(w[j]);
                *reinterpret_cast<s16x8*>(Wl + m * 8) = f;
            }
        }
    }
    __syncthreads();

    // ---- load B-fragments from Wl into registers, then free Wl for albufs
    s16x8 bfr[18];
    #pragma unroll
    for (int ks = 0; ks < 18; ++ks)
        bfr[ks] = *reinterpret_cast<const s16x8*>(Wl + ks * 2048 + st * 8);
    __syncthreads();

    // ---- main GEMM (R8 tiling; trailing barrier dropped on last iter)
    {
        const int wv4 = (tid >> 6) & 3;
        const int quad = lane >> 4, l16 = lane & 15;
        unsigned short* albuf = (unsigned short*)(smem + 8192 + sg * 37376);
        const int col = wv4 * 16 + l16;
        const float bb = biasl[col];
        const unsigned short* xb = xcl + (size_t)b * (XH * XH * 64);
        const int p = st >> 3, part = st & 7;
        const int ntile = (cnt + 31) >> 5;
        const int niter = (ntile + 3) >> 2;
        unsigned short* ob = outc + (size_t)b * (OROWS * 64);

        #pragma unroll 1
        for (int it = 0; it < niter; ++it) {
            const int t = it * 4 + sg;
            const bool live = (t < ntile);
            if (live) {
                int slot = (t << 5) + p;
                int n = (slot < cnt) ? (int)list[slot] : 0;
                const unsigned short* xrow =
                    xb + (((n >> 6) * XH) + (n & 63)) * 64 + part * 8;
                unsigned short* arow = albuf + p * 584 + part * 8;
                #pragma unroll
                for (int tap = 0; tap < 9; ++tap) {
                    int dy = tap / 3, dx = tap - dy * 3;
                    *reinterpret_cast<s16x8*>(arow + tap * 64) =
                        *reinterpret_cast<const s16x8*>(xrow + (dy * XH + dx) * 64);
                }
            }
            __syncthreads();
            if (live) {
                f32x4 acc0 = {0.f, 0.f, 0.f, 0.f}, acc1 = {0.f, 0.f, 0.f, 0.f};
                const unsigned short* ar0 = albuf + l16 * 584 + quad * 8;
                const unsigned short* ar1 = ar0 + 16 * 584;
                #pragma unroll
                for (int ks = 0; ks < 18; ++ks) {
                    s16x8 a0 = *reinterpret_cast<const s16x8*>(ar0 + ks * 32);
                    s16x8 a1 = *reinterpret_cast<const s16x8*>(ar1 + ks * 32);
                    acc0 = __builtin_amdgcn_mfma_f32_16x16x32_bf16(a0, bfr[ks], acc0, 0, 0, 0);
                    acc1 = __builtin_amdgcn_mfma_f32_16x16x32_bf16(a1, bfr[ks], acc1, 0, 0, 0);
                }
                #pragma unroll
                for (int r = 0; r < 4; ++r) {
                    int s0 = (t << 5) + quad * 4 + r;
                    if (s0 < cnt)
                        ob[(size_t)(s0 * 16 + k) * 64 + col] = f2bf(acc0[r] + bb);
                    int s1 = s0 + 16;
                    if (s1 < cnt)
                        ob[(size_t)(s1 * 16 + k) * 64 + col] = f2bf(acc1[r] + bb);
                }
            }
            if (it + 1 < niter) __syncthreads();   // R12: skip trailing drain
        }
    }
}

// ---------------------------------------------------------------------------
// k_scatter (R6): grid 1024. Interleaved outc: row = slotmap[n]*16 + lab[n],
// no prefix/counts needed. 16B gathers, LDS transpose (rows padded to 20
// u16), coalesced f32 stores.
// ---------------------------------------------------------------------------
extern "C" __global__ __launch_bounds__(256)
void k_scatter(const int* __restrict__ labels, const unsigned short* __restrict__ slotmap,
               const unsigned short* __restrict__ outc, float* __restrict__ out)
{
    const int blk = blockIdx.x;
    const int b = blk & 15, chunk = (blk >> 4) & 15, q = blk >> 8;
    const int tid = threadIdx.x;
    __shared__ int sptr[256];
    __shared__ unsigned short tt[256 * 20];     // 10 KB
    const int n0 = chunk * 256;
    {
        int n = n0 + tid;
        sptr[tid] = (int)slotmap[b * NPIX + n] * 16 + labels[b * NPIX + n];
    }
    __syncthreads();
    #pragma unroll
    for (int e0 = 0; e0 < 2; ++e0) {
        int e = e0 * 256 + tid;
        int pix = e >> 1, part = e & 1;
        s16x8 vv = *reinterpret_cast<const s16x8*>(
            outc + ((size_t)b * (OROWS * 64)) + (size_t)sptr[pix] * 64 + q * 16 + part * 8);
        s16x4 lo = {vv[0], vv[1], vv[2], vv[3]};
        s16x4 hi = {vv[4], vv[5], vv[6], vv[7]};
        *reinterpret_cast<s16x4*>(tt + pix * 20 + part * 8) = lo;
        *reinterpret_cast<s16x4*>(tt + pix * 20 + part * 8 + 4) = hi;
    }
    __syncthreads();
    float* ob = out + ((size_t)(b * NOUT + q * 16)) * NPIX + n0;
    #pragma unroll
    for (int oo = 0; oo < 16; ++oo)
        ob[(size_t)oo * NPIX + tid] = bf2f(tt[tid * 20 + oo]);
}

// ---------------------------------------------------------------------------
// Workspace layout (total used 26,419,200 of 39,068,672 B):
//   basekF  @ 0        : 589,824
//   slotmap @ 589824   : 131,072
//   xcl     @ 720896   : 8,921,088
//   outc    @ 9641984  : 16,777,216   (16 images x 8192 interleaved rows x 64)
// ---------------------------------------------------------------------------
extern "C" void kernel_launch(void* const* d_in, const int* in_sizes, int n_in,
                              void* d_out, int out_size, void* d_ws, size_t ws_size,
                              hipStream_t stream)
{
    const float* x      = (const float*)d_in[0];
    const int*   labels = (const int*)d_in[1];
    const float* lw1    = (const float*)d_in[2];
    const float* lb1    = (const float*)d_in[3];
    const float* lw2    = (const float*)d_in[4];
    const float* lb2    = (const float*)d_in[5];
    const float* lw3    = (const float*)d_in[6];
    const float* lb3    = (const float*)d_in[7];
    const float* basek  = (const float*)d_in[8];
    const float* bw1    = (const float*)d_in[9];
    const float* bb1    = (const float*)d_in[10];
    const float* bw2    = (const float*)d_in[11];
    const float* bb2    = (const float*)d_in[12];
    float* out = (float*)d_out;

    char* ws = (char*)d_ws;
    unsigned short* basekF  = (unsigned short*)(ws);
    unsigned short* slotmap = (unsigned short*)(ws + 589824);
    unsigned short* xcl     = (unsigned short*)(ws + 720896);
    unsigned short* outc    = (unsigned short*)(ws + 9641984);

    k_prep_all<<<XH * 16 + 72, 256, 0, stream>>>(x, basek, xcl, basekF);
    k_cm<<<256, 1024, 157952, stream>>>(xcl, labels, lw1, lb1, lw2, lb2, lw3, lb3,
                                        bw1, bb1, bw2, bb2, basekF, slotmap, outc);
    k_scatter<<<1024, 256, 0, stream>>>(labels, slotmap, outc, out);
}